// Round 1
// baseline (138031.848 us; speedup 1.0000x reference)
//
#include <hip/hip_runtime.h>
#include <math.h>

#define BB 32
#define TT 512
#define FF 1024
#define UU 1024

// ---------------------------------------------------------------------------
// Kernel A (gates): for step t, compute
//   gates[b, j] = sigmoid( sum_k xh[b,k] * Wg[k,j] + bg[j] ),  j in [0, 2U)
// where xh = concat(x[:, t, :], h).  Writes:
//   j <  U : rh[b,j]   = gates * h[b,j]     (r gate, pre-multiplied by h)
//   j >= U : ubuf[b,j-U] = gates            (u gate)
// grid = 64 blocks, block = 256 threads; block covers 32 j-columns, all 32 b.
// ---------------------------------------------------------------------------
__global__ __launch_bounds__(256) void gru_gates(
    const float* __restrict__ x,      // [B, T, F]
    const float* __restrict__ Wg,     // [F+U, 2U] row-major
    const float* __restrict__ bg,     // [2U]
    const float* __restrict__ h,      // [B, U]
    float* __restrict__ rh,           // [B, U]
    float* __restrict__ ubuf,         // [B, U]
    int t)
{
    __shared__ float xh[BB][64];      // [b][kk]   8 KB
    __shared__ float wl[64][32];      // [kk][jj]  8 KB
    const int tid  = threadIdx.x;
    const int jloc = tid & 31;        // 0..31 column within tile
    const int b0   = (tid >> 5) * 4;  // 4 batches per thread
    const int j0   = blockIdx.x * 32;

    float acc0 = 0.f, acc1 = 0.f, acc2 = 0.f, acc3 = 0.f;

    for (int k0 = 0; k0 < FF + UU; k0 += 64) {
        // stage xh chunk [32 b][64 k]
        for (int idx = tid; idx < BB * 64; idx += 256) {
            int b = idx >> 6, kk = idx & 63, k = k0 + kk;
            xh[b][kk] = (k < FF)
                ? x[(size_t)b * TT * FF + (size_t)t * FF + k]
                : h[b * UU + (k - FF)];
        }
        // stage W chunk [64 k][32 j]
        for (int idx = tid; idx < 64 * 32; idx += 256) {
            int kk = idx >> 5, jj = idx & 31;
            wl[kk][jj] = Wg[(size_t)(k0 + kk) * (2 * UU) + (j0 + jj)];
        }
        __syncthreads();
        #pragma unroll
        for (int kk = 0; kk < 64; kk += 4) {
            float w0 = wl[kk + 0][jloc];
            float w1 = wl[kk + 1][jloc];
            float w2 = wl[kk + 2][jloc];
            float w3 = wl[kk + 3][jloc];
            float4 a0 = *(const float4*)&xh[b0 + 0][kk];
            float4 a1 = *(const float4*)&xh[b0 + 1][kk];
            float4 a2 = *(const float4*)&xh[b0 + 2][kk];
            float4 a3 = *(const float4*)&xh[b0 + 3][kk];
            acc0 += a0.x * w0 + a0.y * w1 + a0.z * w2 + a0.w * w3;
            acc1 += a1.x * w0 + a1.y * w1 + a1.z * w2 + a1.w * w3;
            acc2 += a2.x * w0 + a2.y * w1 + a2.z * w2 + a2.w * w3;
            acc3 += a3.x * w0 + a3.y * w1 + a3.z * w2 + a3.w * w3;
        }
        __syncthreads();
    }

    const int j = j0 + jloc;
    const float bias = bg[j];
    float g[4] = {acc0 + bias, acc1 + bias, acc2 + bias, acc3 + bias};
    #pragma unroll
    for (int i = 0; i < 4; ++i) {
        int b = b0 + i;
        float s = 1.f / (1.f + expf(-g[i]));
        if (j < UU) rh[b * UU + j] = s * h[b * UU + j];
        else        ubuf[b * UU + (j - UU)] = s;
    }
}

// ---------------------------------------------------------------------------
// Kernel B (candidate + state update): for step t, compute
//   c[b,j]  = tanh( sum_k xrh[b,k] * Wc[k,j] + bc[j] ),  xrh = concat(x_t, rh)
//   h_new   = u*h + (1-u)*c ;  h <- h_new ;  out[b,t,j] = h_new
// grid = 32 blocks, block = 256 threads; block covers 32 j-columns, all 32 b.
// ---------------------------------------------------------------------------
__global__ __launch_bounds__(256) void gru_cand(
    const float* __restrict__ x,      // [B, T, F]
    const float* __restrict__ Wc,     // [F+U, U] row-major
    const float* __restrict__ bc,     // [U]
    const float* __restrict__ rh,     // [B, U]
    const float* __restrict__ ubuf,   // [B, U]
    float* __restrict__ h,            // [B, U] (updated in place)
    float* __restrict__ out,          // [B, T, U]
    int t)
{
    __shared__ float xh[BB][64];
    __shared__ float wl[64][32];
    const int tid  = threadIdx.x;
    const int jloc = tid & 31;
    const int b0   = (tid >> 5) * 4;
    const int j0   = blockIdx.x * 32;

    float acc0 = 0.f, acc1 = 0.f, acc2 = 0.f, acc3 = 0.f;

    for (int k0 = 0; k0 < FF + UU; k0 += 64) {
        for (int idx = tid; idx < BB * 64; idx += 256) {
            int b = idx >> 6, kk = idx & 63, k = k0 + kk;
            xh[b][kk] = (k < FF)
                ? x[(size_t)b * TT * FF + (size_t)t * FF + k]
                : rh[b * UU + (k - FF)];
        }
        for (int idx = tid; idx < 64 * 32; idx += 256) {
            int kk = idx >> 5, jj = idx & 31;
            wl[kk][jj] = Wc[(size_t)(k0 + kk) * UU + (j0 + jj)];
        }
        __syncthreads();
        #pragma unroll
        for (int kk = 0; kk < 64; kk += 4) {
            float w0 = wl[kk + 0][jloc];
            float w1 = wl[kk + 1][jloc];
            float w2 = wl[kk + 2][jloc];
            float w3 = wl[kk + 3][jloc];
            float4 a0 = *(const float4*)&xh[b0 + 0][kk];
            float4 a1 = *(const float4*)&xh[b0 + 1][kk];
            float4 a2 = *(const float4*)&xh[b0 + 2][kk];
            float4 a3 = *(const float4*)&xh[b0 + 3][kk];
            acc0 += a0.x * w0 + a0.y * w1 + a0.z * w2 + a0.w * w3;
            acc1 += a1.x * w0 + a1.y * w1 + a1.z * w2 + a1.w * w3;
            acc2 += a2.x * w0 + a2.y * w1 + a2.z * w2 + a2.w * w3;
            acc3 += a3.x * w0 + a3.y * w1 + a3.z * w2 + a3.w * w3;
        }
        __syncthreads();
    }

    const int j = j0 + jloc;
    const float bias = bc[j];
    float cpre[4] = {acc0 + bias, acc1 + bias, acc2 + bias, acc3 + bias};
    #pragma unroll
    for (int i = 0; i < 4; ++i) {
        int b = b0 + i;
        float c  = tanhf(cpre[i]);
        float u  = ubuf[b * UU + j];
        float hv = h[b * UU + j];
        float hn = u * hv + (1.f - u) * c;
        h[b * UU + j] = hn;
        out[(size_t)b * TT * UU + (size_t)t * UU + j] = hn;
    }
}

extern "C" void kernel_launch(void* const* d_in, const int* in_sizes, int n_in,
                              void* d_out, int out_size, void* d_ws, size_t ws_size,
                              hipStream_t stream) {
    const float* x  = (const float*)d_in[0];   // inputs      [B, T, F]
    const float* Wg = (const float*)d_in[1];   // gate_kernel [F+U, 2U]
    const float* bg = (const float*)d_in[2];   // gate_bias   [2U]
    const float* Wc = (const float*)d_in[3];   // cand_kernel [F+U, U]
    const float* bc = (const float*)d_in[4];   // cand_bias   [U]
    float* out = (float*)d_out;

    float* h    = (float*)d_ws;                // [B, U]
    float* rh   = h  + BB * UU;                // [B, U]
    float* ubuf = rh + BB * UU;                // [B, U]

    hipMemsetAsync(h, 0, BB * UU * sizeof(float), stream);  // h0 = 0

    for (int t = 0; t < TT; ++t) {
        gru_gates<<<64, 256, 0, stream>>>(x, Wg, bg, h, rh, ubuf, t);
        gru_cand <<<32, 256, 0, stream>>>(x, Wc, bc, rh, ubuf, h, out, t);
    }
}

// Round 2
// 5307.099 us; speedup vs baseline: 26.0089x; 26.0089x over previous
//
#include <hip/hip_runtime.h>
#include <math.h>

#define BB 32
#define TT 512
#define FF 1024
#define UU 1024

typedef __attribute__((ext_vector_type(8))) short s8v;    // 8 x bf16 (4 VGPR)
typedef __attribute__((ext_vector_type(4))) float f4v;    // 4 x f32

static __device__ __forceinline__ unsigned short f2bf(float f) {
    unsigned int u = __builtin_bit_cast(unsigned int, f);
    u += 0x7fff + ((u >> 16) & 1);          // RNE
    return (unsigned short)(u >> 16);
}
static __device__ __forceinline__ float bf2f(unsigned short b) {
    unsigned int u = ((unsigned int)b) << 16;
    return __builtin_bit_cast(float, u);
}

// ---------------------------------------------------------------------------
// fp32 -> bf16 elementwise (vectorized, 4/thread)
// ---------------------------------------------------------------------------
__global__ __launch_bounds__(256) void cvt_bf16(
    const float* __restrict__ in, unsigned short* __restrict__ out, int n4)
{
    int i = blockIdx.x * 256 + threadIdx.x;
    if (i < n4) {
        float4 v = ((const float4*)in)[i];
        ushort4 o;
        o.x = f2bf(v.x); o.y = f2bf(v.y); o.z = f2bf(v.z); o.w = f2bf(v.w);
        ((ushort4*)out)[i] = o;
    }
}

// ---------------------------------------------------------------------------
// Transpose + convert: W [ROWS k][COLS n] f32 -> WT [COLS][ROWS] bf16
// ---------------------------------------------------------------------------
template<int ROWS, int COLS>
__global__ __launch_bounds__(256) void transpose_bf16(
    const float* __restrict__ W, unsigned short* __restrict__ WT)
{
    __shared__ float tl[32][33];
    const int tx = threadIdx.x, ty = threadIdx.y;   // block (32, 8)
    const int bx = blockIdx.x, by = blockIdx.y;
    #pragma unroll
    for (int i = 0; i < 4; ++i) {
        int r = by * 32 + ty + i * 8;
        int c = bx * 32 + tx;
        tl[ty + i * 8][tx] = W[(size_t)r * COLS + c];
    }
    __syncthreads();
    #pragma unroll
    for (int i = 0; i < 4; ++i) {
        int n = bx * 32 + ty + i * 8;
        int k = by * 32 + tx;
        WT[(size_t)n * ROWS + k] = f2bf(tl[tx][ty + i * 8]);
    }
}

// ---------------------------------------------------------------------------
// Precompute GEMM: C[M,N] bf16 = A[M,1024] bf16 @ B, with B given transposed
// as BT[N][2048] (only k = 0..1023 used).  128x128 tile, 4 waves, 16x16x32.
// ---------------------------------------------------------------------------
__global__ __launch_bounds__(256) void gemm_xproj(
    const unsigned short* __restrict__ A,    // [M][1024]
    const unsigned short* __restrict__ BT,   // [N][2048]
    unsigned short* __restrict__ C,          // [M][N]
    int N)
{
    __shared__ unsigned short Al[128][72];   // pad 64->72 (144 B rows, 16B-aligned)
    __shared__ unsigned short Bl[128][72];
    const int tid  = threadIdx.x;
    const int lane = tid & 63;
    const int wave = tid >> 6;
    const int l15  = lane & 15;
    const int kg   = lane >> 4;              // 0..3
    const int m0   = blockIdx.y * 128;
    const int n0   = blockIdx.x * 128;
    const int rowOff = (wave >> 1) * 64;
    const int colOff = (wave & 1) * 64;

    f4v acc[4][4];
    #pragma unroll
    for (int m = 0; m < 4; ++m)
        #pragma unroll
        for (int n = 0; n < 4; ++n) acc[m][n] = (f4v){0.f, 0.f, 0.f, 0.f};

    for (int k0 = 0; k0 < 1024; k0 += 64) {
        #pragma unroll
        for (int it = 0; it < 4; ++it) {
            int c = tid + it * 256;          // 1024 chunks of 16 B
            int r = c >> 3, off = (c & 7) * 8;
            *(s8v*)&Al[r][off] = *(const s8v*)(A + (size_t)(m0 + r) * 1024 + k0 + off);
            *(s8v*)&Bl[r][off] = *(const s8v*)(BT + (size_t)(n0 + r) * 2048 + k0 + off);
        }
        __syncthreads();
        #pragma unroll
        for (int ks = 0; ks < 2; ++ks) {
            s8v a[4], b[4];
            #pragma unroll
            for (int m = 0; m < 4; ++m)
                a[m] = *(const s8v*)&Al[rowOff + m * 16 + l15][ks * 32 + kg * 8];
            #pragma unroll
            for (int n = 0; n < 4; ++n)
                b[n] = *(const s8v*)&Bl[colOff + n * 16 + l15][ks * 32 + kg * 8];
            #pragma unroll
            for (int m = 0; m < 4; ++m)
                #pragma unroll
                for (int n = 0; n < 4; ++n)
                    acc[m][n] = __builtin_amdgcn_mfma_f32_16x16x32_bf16(a[m], b[n], acc[m][n], 0, 0, 0);
        }
        __syncthreads();
    }
    #pragma unroll
    for (int m = 0; m < 4; ++m)
        #pragma unroll
        for (int n = 0; n < 4; ++n)
            #pragma unroll
            for (int i = 0; i < 4; ++i) {
                int row = m0 + rowOff + m * 16 + kg * 4 + i;
                int col = n0 + colOff + n * 16 + l15;
                C[(size_t)row * N + col] = f2bf(acc[m][n][i]);
            }
}

// ---------------------------------------------------------------------------
// Per-step gates: gates[32, 2048] = hb @ WgT[:,1024:] + Xg_t + bg -> sigmoid
//   j <  1024: rhb = bf16(sig * h)   (r-gate)
//   j >= 1024: ubuf = sig            (u-gate, fp32)
// grid 128 blocks (16 cols each) x 256 thr (4 waves, K-split 256/wave).
// ---------------------------------------------------------------------------
__global__ __launch_bounds__(256) void gru_gates2(
    const unsigned short* __restrict__ hb,    // [32][1024] bf16
    const unsigned short* __restrict__ WgT,   // [2048 n][2048 k] bf16
    const unsigned short* __restrict__ Xgb,   // [16384][2048] bf16
    const float* __restrict__ bg,             // [2048]
    const float* __restrict__ h,              // [32][1024] f32
    unsigned short* __restrict__ rhb,         // [32][1024] bf16
    float* __restrict__ ubuf,                 // [32][1024] f32
    int t)
{
    __shared__ unsigned short hb_l[32][1032]; // pad 1024->1032 (2064 B rows)
    __shared__ unsigned short Wl[16][1032];
    __shared__ float red[4][32][16];
    const int tid  = threadIdx.x;
    const int lane = tid & 63;
    const int wave = tid >> 6;
    const int l15  = lane & 15;
    const int kg   = lane >> 4;
    const int j0   = blockIdx.x * 16;

    // stage hb [32][1024]: 4096 chunks of 16 B
    #pragma unroll
    for (int it = 0; it < 16; ++it) {
        int c = tid + it * 256;
        int r = c >> 7, off = (c & 127) * 8;
        *(s8v*)&hb_l[r][off] = *(const s8v*)(hb + (size_t)r * 1024 + off);
    }
    // stage W cols j0..j0+15, recurrent k-slice: 2048 chunks of 16 B
    #pragma unroll
    for (int it = 0; it < 8; ++it) {
        int c = tid + it * 256;
        int r = c >> 7, off = (c & 127) * 8;
        *(s8v*)&Wl[r][off] = *(const s8v*)(WgT + (size_t)(j0 + r) * 2048 + 1024 + off);
    }
    __syncthreads();

    f4v acc0 = (f4v){0.f,0.f,0.f,0.f}, acc1 = (f4v){0.f,0.f,0.f,0.f};
    const int kbase = wave * 256;
    #pragma unroll
    for (int kk = 0; kk < 8; ++kk) {
        int k = kbase + kk * 32 + kg * 8;
        s8v a0 = *(const s8v*)&hb_l[l15][k];
        s8v a1 = *(const s8v*)&hb_l[16 + l15][k];
        s8v b  = *(const s8v*)&Wl[l15][k];
        acc0 = __builtin_amdgcn_mfma_f32_16x16x32_bf16(a0, b, acc0, 0, 0, 0);
        acc1 = __builtin_amdgcn_mfma_f32_16x16x32_bf16(a1, b, acc1, 0, 0, 0);
    }
    #pragma unroll
    for (int i = 0; i < 4; ++i) {
        red[wave][kg * 4 + i][l15]      = acc0[i];
        red[wave][16 + kg * 4 + i][l15] = acc1[i];
    }
    __syncthreads();

    for (int e = tid; e < 512; e += 256) {
        int b = e >> 4, col = e & 15;
        int j = j0 + col;
        float pre = red[0][b][col] + red[1][b][col] + red[2][b][col] + red[3][b][col];
        pre += bf2f(Xgb[((size_t)b * TT + t) * 2048 + j]) + bg[j];
        float s = 1.f / (1.f + __expf(-pre));
        if (j < UU) rhb[b * UU + j] = f2bf(s * h[b * UU + j]);
        else        ubuf[b * UU + (j - UU)] = s;
    }
}

// ---------------------------------------------------------------------------
// Per-step candidate + update: c = tanh(rhb @ WcT[:,1024:] + Xc_t + bc)
//   h_new = u*h + (1-u)*c ; h, hb <- h_new ; out[b,t,:] = h_new
// grid 64 blocks (16 cols each) x 256 thr.
// ---------------------------------------------------------------------------
__global__ __launch_bounds__(256) void gru_cand2(
    const unsigned short* __restrict__ rhb,   // [32][1024] bf16
    const unsigned short* __restrict__ WcT,   // [1024 n][2048 k] bf16
    const unsigned short* __restrict__ Xcb,   // [16384][1024] bf16
    const float* __restrict__ bc,             // [1024]
    const float* __restrict__ ubuf,           // [32][1024] f32
    float* __restrict__ h,                    // [32][1024] f32 (in/out)
    unsigned short* __restrict__ hb,          // [32][1024] bf16 (out)
    float* __restrict__ out,                  // [B][T][U] f32
    int t)
{
    __shared__ unsigned short rh_l[32][1032];
    __shared__ unsigned short Wl[16][1032];
    __shared__ float red[4][32][16];
    const int tid  = threadIdx.x;
    const int lane = tid & 63;
    const int wave = tid >> 6;
    const int l15  = lane & 15;
    const int kg   = lane >> 4;
    const int j0   = blockIdx.x * 16;

    #pragma unroll
    for (int it = 0; it < 16; ++it) {
        int c = tid + it * 256;
        int r = c >> 7, off = (c & 127) * 8;
        *(s8v*)&rh_l[r][off] = *(const s8v*)(rhb + (size_t)r * 1024 + off);
    }
    #pragma unroll
    for (int it = 0; it < 8; ++it) {
        int c = tid + it * 256;
        int r = c >> 7, off = (c & 127) * 8;
        *(s8v*)&Wl[r][off] = *(const s8v*)(WcT + (size_t)(j0 + r) * 2048 + 1024 + off);
    }
    __syncthreads();

    f4v acc0 = (f4v){0.f,0.f,0.f,0.f}, acc1 = (f4v){0.f,0.f,0.f,0.f};
    const int kbase = wave * 256;
    #pragma unroll
    for (int kk = 0; kk < 8; ++kk) {
        int k = kbase + kk * 32 + kg * 8;
        s8v a0 = *(const s8v*)&rh_l[l15][k];
        s8v a1 = *(const s8v*)&rh_l[16 + l15][k];
        s8v b  = *(const s8v*)&Wl[l15][k];
        acc0 = __builtin_amdgcn_mfma_f32_16x16x32_bf16(a0, b, acc0, 0, 0, 0);
        acc1 = __builtin_amdgcn_mfma_f32_16x16x32_bf16(a1, b, acc1, 0, 0, 0);
    }
    #pragma unroll
    for (int i = 0; i < 4; ++i) {
        red[wave][kg * 4 + i][l15]      = acc0[i];
        red[wave][16 + kg * 4 + i][l15] = acc1[i];
    }
    __syncthreads();

    for (int e = tid; e < 512; e += 256) {
        int b = e >> 4, col = e & 15;
        int j = j0 + col;
        float pre = red[0][b][col] + red[1][b][col] + red[2][b][col] + red[3][b][col];
        pre += bf2f(Xcb[((size_t)b * TT + t) * 1024 + j]) + bc[j];
        float cv = tanhf(pre);
        float u  = ubuf[b * UU + j];
        float hv = h[b * UU + j];
        float hn = u * hv + (1.f - u) * cv;
        h[b * UU + j]  = hn;
        hb[b * UU + j] = f2bf(hn);
        out[((size_t)b * TT + t) * UU + j] = hn;
    }
}

// ===========================================================================
// Legacy fallback (round-1 kernels) — used only if ws_size is too small.
// ===========================================================================
__global__ __launch_bounds__(256) void gru_gates(
    const float* __restrict__ x, const float* __restrict__ Wg,
    const float* __restrict__ bg, const float* __restrict__ h,
    float* __restrict__ rh, float* __restrict__ ubuf, int t)
{
    __shared__ float xh[BB][64];
    __shared__ float wl[64][32];
    const int tid = threadIdx.x, jloc = tid & 31, b0 = (tid >> 5) * 4;
    const int j0 = blockIdx.x * 32;
    float acc0 = 0.f, acc1 = 0.f, acc2 = 0.f, acc3 = 0.f;
    for (int k0 = 0; k0 < FF + UU; k0 += 64) {
        for (int idx = tid; idx < BB * 64; idx += 256) {
            int b = idx >> 6, kk = idx & 63, k = k0 + kk;
            xh[b][kk] = (k < FF) ? x[(size_t)b * TT * FF + (size_t)t * FF + k]
                                 : h[b * UU + (k - FF)];
        }
        for (int idx = tid; idx < 64 * 32; idx += 256) {
            int kk = idx >> 5, jj = idx & 31;
            wl[kk][jj] = Wg[(size_t)(k0 + kk) * (2 * UU) + (j0 + jj)];
        }
        __syncthreads();
        #pragma unroll
        for (int kk = 0; kk < 64; kk += 4) {
            float w0 = wl[kk][jloc], w1 = wl[kk+1][jloc], w2 = wl[kk+2][jloc], w3 = wl[kk+3][jloc];
            float4 a0 = *(const float4*)&xh[b0+0][kk], a1 = *(const float4*)&xh[b0+1][kk];
            float4 a2 = *(const float4*)&xh[b0+2][kk], a3 = *(const float4*)&xh[b0+3][kk];
            acc0 += a0.x*w0 + a0.y*w1 + a0.z*w2 + a0.w*w3;
            acc1 += a1.x*w0 + a1.y*w1 + a1.z*w2 + a1.w*w3;
            acc2 += a2.x*w0 + a2.y*w1 + a2.z*w2 + a2.w*w3;
            acc3 += a3.x*w0 + a3.y*w1 + a3.z*w2 + a3.w*w3;
        }
        __syncthreads();
    }
    const int j = j0 + jloc;
    const float bias = bg[j];
    float g[4] = {acc0+bias, acc1+bias, acc2+bias, acc3+bias};
    #pragma unroll
    for (int i = 0; i < 4; ++i) {
        int b = b0 + i;
        float s = 1.f / (1.f + expf(-g[i]));
        if (j < UU) rh[b * UU + j] = s * h[b * UU + j];
        else        ubuf[b * UU + (j - UU)] = s;
    }
}

__global__ __launch_bounds__(256) void gru_cand(
    const float* __restrict__ x, const float* __restrict__ Wc,
    const float* __restrict__ bc, const float* __restrict__ rh,
    const float* __restrict__ ubuf, float* __restrict__ h,
    float* __restrict__ out, int t)
{
    __shared__ float xh[BB][64];
    __shared__ float wl[64][32];
    const int tid = threadIdx.x, jloc = tid & 31, b0 = (tid >> 5) * 4;
    const int j0 = blockIdx.x * 32;
    float acc0 = 0.f, acc1 = 0.f, acc2 = 0.f, acc3 = 0.f;
    for (int k0 = 0; k0 < FF + UU; k0 += 64) {
        for (int idx = tid; idx < BB * 64; idx += 256) {
            int b = idx >> 6, kk = idx & 63, k = k0 + kk;
            xh[b][kk] = (k < FF) ? x[(size_t)b * TT * FF + (size_t)t * FF + k]
                                 : rh[b * UU + (k - FF)];
        }
        for (int idx = tid; idx < 64 * 32; idx += 256) {
            int kk = idx >> 5, jj = idx & 31;
            wl[kk][jj] = Wc[(size_t)(k0 + kk) * UU + (j0 + jj)];
        }
        __syncthreads();
        #pragma unroll
        for (int kk = 0; kk < 64; kk += 4) {
            float w0 = wl[kk][jloc], w1 = wl[kk+1][jloc], w2 = wl[kk+2][jloc], w3 = wl[kk+3][jloc];
            float4 a0 = *(const float4*)&xh[b0+0][kk], a1 = *(const float4*)&xh[b0+1][kk];
            float4 a2 = *(const float4*)&xh[b0+2][kk], a3 = *(const float4*)&xh[b0+3][kk];
            acc0 += a0.x*w0 + a0.y*w1 + a0.z*w2 + a0.w*w3;
            acc1 += a1.x*w0 + a1.y*w1 + a1.z*w2 + a1.w*w3;
            acc2 += a2.x*w0 + a2.y*w1 + a2.z*w2 + a2.w*w3;
            acc3 += a3.x*w0 + a3.y*w1 + a3.z*w2 + a3.w*w3;
        }
        __syncthreads();
    }
    const int j = j0 + jloc;
    const float bias = bc[j];
    float cpre[4] = {acc0+bias, acc1+bias, acc2+bias, acc3+bias};
    #pragma unroll
    for (int i = 0; i < 4; ++i) {
        int b = b0 + i;
        float c  = tanhf(cpre[i]);
        float u  = ubuf[b * UU + j];
        float hv = h[b * UU + j];
        float hn = u * hv + (1.f - u) * c;
        h[b * UU + j] = hn;
        out[(size_t)b * TT * UU + (size_t)t * UU + j] = hn;
    }
}

// ===========================================================================
extern "C" void kernel_launch(void* const* d_in, const int* in_sizes, int n_in,
                              void* d_out, int out_size, void* d_ws, size_t ws_size,
                              hipStream_t stream) {
    const float* x  = (const float*)d_in[0];   // [B, T, F]
    const float* Wg = (const float*)d_in[1];   // [F+U, 2U]
    const float* bg = (const float*)d_in[2];   // [2U]
    const float* Wc = (const float*)d_in[3];   // [F+U, U]
    const float* bc = (const float*)d_in[4];   // [U]
    float* out = (float*)d_out;

    // Workspace layout (bf16 plan)
    const size_t XB_B  = (size_t)BB * TT * FF * 2;          //  33,554,432
    const size_t WGT_B = (size_t)2 * UU * (FF + UU) * 2;    //   8,388,608
    const size_t WCT_B = (size_t)UU * (FF + UU) * 2;        //   4,194,304
    const size_t XG_B  = (size_t)BB * TT * 2 * UU * 2;      //  67,108,864
    const size_t XC_B  = (size_t)BB * TT * UU * 2;          //  33,554,432
    const size_t H_B   = (size_t)BB * UU * 4;
    const size_t HB_B  = (size_t)BB * UU * 2;
    const size_t NEED  = XB_B + WGT_B + WCT_B + XG_B + XC_B + H_B + HB_B * 2 + H_B;

    if (ws_size >= NEED) {
        char* p = (char*)d_ws;
        unsigned short* xb  = (unsigned short*)p;            p += XB_B;
        unsigned short* WgT = (unsigned short*)p;            p += WGT_B;
        unsigned short* WcT = (unsigned short*)p;            p += WCT_B;
        unsigned short* Xgb = (unsigned short*)p;            p += XG_B;
        unsigned short* Xcb = (unsigned short*)p;            p += XC_B;
        float*          h   = (float*)p;                     p += H_B;
        unsigned short* hb  = (unsigned short*)p;            p += HB_B;
        unsigned short* rhb = (unsigned short*)p;            p += HB_B;
        float*          ub  = (float*)p;                     p += H_B;

        // ---- one-time prep (per launch) ----
        cvt_bf16<<<(BB * TT * FF / 4 + 255) / 256, 256, 0, stream>>>(x, xb, BB * TT * FF / 4);
        transpose_bf16<FF + UU, 2 * UU><<<dim3(64, 64), dim3(32, 8), 0, stream>>>(Wg, WgT);
        transpose_bf16<FF + UU, UU>    <<<dim3(32, 64), dim3(32, 8), 0, stream>>>(Wc, WcT);
        gemm_xproj<<<dim3(2 * UU / 128, BB * TT / 128), 256, 0, stream>>>(xb, WgT, Xgb, 2 * UU);
        gemm_xproj<<<dim3(UU / 128,     BB * TT / 128), 256, 0, stream>>>(xb, WcT, Xcb, UU);
        hipMemsetAsync(h,  0, H_B,  stream);
        hipMemsetAsync(hb, 0, HB_B, stream);

        // ---- recurrence ----
        for (int t = 0; t < TT; ++t) {
            gru_gates2<<<128, 256, 0, stream>>>(hb, WgT, Xgb, bg, h, rhb, ub, t);
            gru_cand2 <<< 64, 256, 0, stream>>>(rhb, WcT, Xcb, bc, ub, h, hb, out, t);
        }
    } else {
        // legacy fp32 path
        float* h    = (float*)d_ws;
        float* rh   = h  + BB * UU;
        float* ubuf = rh + BB * UU;
        hipMemsetAsync(h, 0, BB * UU * sizeof(float), stream);
        for (int t = 0; t < TT; ++t) {
            gru_gates<<<64, 256, 0, stream>>>(x, Wg, bg, h, rh, ubuf, t);
            gru_cand <<<32, 256, 0, stream>>>(x, Wc, bc, rh, ubuf, h, out, t);
        }
    }
}